// Round 6
// baseline (441.673 us; speedup 1.0000x reference)
//
#include <hip/hip_runtime.h>
#include <math.h>

#define HID 128
#define NEG_SLOPE 0.2f

// ---------------- edge dtype detection ----------------
// Reference declares edges_idx as int64; harness may deliver int64 or int32.
// If int64 (values < 2^31), every odd int32 word (hi word) is 0. For real
// int32 edge data, P(512 sampled edge values all == 0) ~ (1/50000)^512 ~ 0.
// (Round-5 evidence: identical outputs across int32-read and probed builds
//  => probe resolves is64=0 on this harness; kept for robustness.)
__global__ void detect64_kernel(const int* __restrict__ e32, int* __restrict__ is64,
                                long long nwords32) {
    int lane = threadIdx.x & 63;
    int nz = 0;
    #pragma unroll
    for (int q = 0; q < 8; ++q) {
        long long idx = 2LL * (lane * 8 + q) + 1;
        if (idx < nwords32) nz |= (e32[idx] != 0);
    }
    unsigned long long b = __ballot(nz);
    if (lane == 0) *is64 = (b == 0ULL) ? 1 : 0;
}

__device__ __forceinline__ int eload(const void* edges, int is64, long long i) {
    return is64 ? (int)((const long long*)edges)[i] : ((const int*)edges)[i];
}

// ---------------- CSR build ----------------

__global__ void zero_cnt_kernel(int* __restrict__ cnt, int n) {
    int i = blockIdx.x * blockDim.x + threadIdx.x;
    if (i < n) cnt[i] = 0;
}

__global__ void hist_kernel(const void* __restrict__ edges, const int* __restrict__ is64p,
                            int* __restrict__ cnt, int e) {
    int i = blockIdx.x * blockDim.x + threadIdx.x;
    if (i < e) {
        int is64 = *is64p;
        int d = eload(edges, is64, (long long)e + i);   // dst row
        atomicAdd(&cnt[d], 1);
    }
}

// hierarchical exclusive scan of cnt[0..n) -> off/cursor; off[n] = total
__global__ __launch_bounds__(256) void scan1_kernel(const int* __restrict__ cnt,
                                                    int* __restrict__ tmp,
                                                    int* __restrict__ partials, int n) {
    __shared__ int s[256];
    const int t = threadIdx.x;
    const int i0 = blockIdx.x * 1024 + t * 4;
    int v0 = (i0 + 0 < n) ? cnt[i0 + 0] : 0;
    int v1 = (i0 + 1 < n) ? cnt[i0 + 1] : 0;
    int v2 = (i0 + 2 < n) ? cnt[i0 + 2] : 0;
    int v3 = (i0 + 3 < n) ? cnt[i0 + 3] : 0;
    int sum = v0 + v1 + v2 + v3;
    s[t] = sum;
    __syncthreads();
    for (int d = 1; d < 256; d <<= 1) {
        int tt = (t >= d) ? s[t - d] : 0;
        __syncthreads();
        s[t] += tt;
        __syncthreads();
    }
    int run = s[t] - sum;
    if (t == 255) partials[blockIdx.x] = s[255];
    if (i0 + 0 < n) tmp[i0 + 0] = run; run += v0;
    if (i0 + 1 < n) tmp[i0 + 1] = run; run += v1;
    if (i0 + 2 < n) tmp[i0 + 2] = run; run += v2;
    if (i0 + 3 < n) tmp[i0 + 3] = run;
}

// scan2: one 64-lane wave scans (<=64) chunk partials in-place (exclusive).
__global__ void scan2_kernel(int* __restrict__ partials, int nchunks, int* __restrict__ off_n) {
    int lane = threadIdx.x;
    int orig = (lane < nchunks) ? partials[lane] : 0;
    int v = orig;
    for (int d = 1; d < 64; d <<= 1) {
        int t = __shfl_up(v, d);
        if (lane >= d) v += t;
    }
    if (lane < nchunks) partials[lane] = v - orig;
    if (lane == 63) *off_n = v;
}

__global__ void scan3_kernel(const int* __restrict__ tmp, const int* __restrict__ partials,
                             int* __restrict__ off, int* __restrict__ cursor, int n) {
    int i = blockIdx.x * blockDim.x + threadIdx.x;
    if (i < n) {
        int v = tmp[i] + partials[i >> 10];
        off[i] = v;
        cursor[i] = v;
    }
}

__global__ void scatter_kernel(const void* __restrict__ edges, const int* __restrict__ is64p,
                               int* __restrict__ cursor, int* __restrict__ esrc, int e) {
    int i = blockIdx.x * blockDim.x + threadIdx.x;
    if (i < e) {
        int is64 = *is64p;
        int s = eload(edges, is64, i);                   // src row
        int d = eload(edges, is64, (long long)e + i);    // dst row
        int p = atomicAdd(&cursor[d], 1);
        esrc[p] = s;
    }
}

// ---------------- dual GEMM: OL = X @ WL, OR = X @ WR (one block does both) ----
// block: 256 threads (4 waves), tile 64 rows x 128 cols, BOTH outputs.
// Per-thread: 8 rows x 4 cols per side (64 acc regs). k unrolled x4 so both
// X and W come out of LDS as ds_read_b128. LDS 64KB -> 2 blocks/CU.

__global__ __launch_bounds__(256) void gemm_dual_kernel(const float* __restrict__ X,
                                                        const float* __restrict__ WL,
                                                        const float* __restrict__ WR,
                                                        float* __restrict__ OL,
                                                        float* __restrict__ ORp, int n) {
    __shared__ float Xs[64][128];
    __shared__ float Ws[2][32][128];
    const int tid = threadIdx.x;
    const int row0 = blockIdx.x * 64;

    // stage X tile (zero-pad OOB rows)
    #pragma unroll
    for (int i = tid * 4; i < 64 * 128; i += 256 * 4) {
        int r = i >> 7, c = i & 127;
        float4 v = make_float4(0.f, 0.f, 0.f, 0.f);
        if (row0 + r < n) v = *(const float4*)&X[(size_t)(row0 + r) * HID + c];
        *(float4*)&Xs[r][c] = v;
    }

    const int tr = tid >> 5;   // 0..7 -> rows tr*8 .. tr*8+7
    const int tc = tid & 31;   // cols tc*4 .. tc*4+3
    float accL[8][4] = {};
    float accR[8][4] = {};

    for (int kt = 0; kt < 4; ++kt) {
        __syncthreads();  // covers X stage (kt=0); protects Ws reuse (kt>0)
        #pragma unroll
        for (int i = tid * 4; i < 2 * 32 * 128; i += 256 * 4) {
            int w = i >> 12;
            int rem = i & 4095;
            int k2 = rem >> 7, c = rem & 127;
            const float* __restrict__ Wp = w ? WR : WL;
            *(float4*)&Ws[w][k2][c] = *(const float4*)&Wp[(size_t)(kt * 32 + k2) * 128 + c];
        }
        __syncthreads();

        #pragma unroll
        for (int k4 = 0; k4 < 32; k4 += 4) {
            float4 wl[4], wr[4];
            #pragma unroll
            for (int q = 0; q < 4; ++q) {
                wl[q] = *(const float4*)&Ws[0][k4 + q][tc * 4];
                wr[q] = *(const float4*)&Ws[1][k4 + q][tc * 4];
            }
            #pragma unroll
            for (int r = 0; r < 8; ++r) {
                // FIX (round 5): global k column = kt*32 + k4. Round 2-5 read
                // column k4 only (X cols 32..127 never used) -> err 1.18.
                float4 xv = *(const float4*)&Xs[tr * 8 + r][kt * 32 + k4];
                accL[r][0] = fmaf(xv.x, wl[0].x, accL[r][0]);
                accL[r][1] = fmaf(xv.x, wl[0].y, accL[r][1]);
                accL[r][2] = fmaf(xv.x, wl[0].z, accL[r][2]);
                accL[r][3] = fmaf(xv.x, wl[0].w, accL[r][3]);
                accR[r][0] = fmaf(xv.x, wr[0].x, accR[r][0]);
                accR[r][1] = fmaf(xv.x, wr[0].y, accR[r][1]);
                accR[r][2] = fmaf(xv.x, wr[0].z, accR[r][2]);
                accR[r][3] = fmaf(xv.x, wr[0].w, accR[r][3]);

                accL[r][0] = fmaf(xv.y, wl[1].x, accL[r][0]);
                accL[r][1] = fmaf(xv.y, wl[1].y, accL[r][1]);
                accL[r][2] = fmaf(xv.y, wl[1].z, accL[r][2]);
                accL[r][3] = fmaf(xv.y, wl[1].w, accL[r][3]);
                accR[r][0] = fmaf(xv.y, wr[1].x, accR[r][0]);
                accR[r][1] = fmaf(xv.y, wr[1].y, accR[r][1]);
                accR[r][2] = fmaf(xv.y, wr[1].z, accR[r][2]);
                accR[r][3] = fmaf(xv.y, wr[1].w, accR[r][3]);

                accL[r][0] = fmaf(xv.z, wl[2].x, accL[r][0]);
                accL[r][1] = fmaf(xv.z, wl[2].y, accL[r][1]);
                accL[r][2] = fmaf(xv.z, wl[2].z, accL[r][2]);
                accL[r][3] = fmaf(xv.z, wl[2].w, accL[r][3]);
                accR[r][0] = fmaf(xv.z, wr[2].x, accR[r][0]);
                accR[r][1] = fmaf(xv.z, wr[2].y, accR[r][1]);
                accR[r][2] = fmaf(xv.z, wr[2].z, accR[r][2]);
                accR[r][3] = fmaf(xv.z, wr[2].w, accR[r][3]);

                accL[r][0] = fmaf(xv.w, wl[3].x, accL[r][0]);
                accL[r][1] = fmaf(xv.w, wl[3].y, accL[r][1]);
                accL[r][2] = fmaf(xv.w, wl[3].z, accL[r][2]);
                accL[r][3] = fmaf(xv.w, wl[3].w, accL[r][3]);
                accR[r][0] = fmaf(xv.w, wr[3].x, accR[r][0]);
                accR[r][1] = fmaf(xv.w, wr[3].y, accR[r][1]);
                accR[r][2] = fmaf(xv.w, wr[3].z, accR[r][2]);
                accR[r][3] = fmaf(xv.w, wr[3].w, accR[r][3]);
            }
        }
    }

    #pragma unroll
    for (int r = 0; r < 8; ++r) {
        int row = row0 + tr * 8 + r;
        if (row < n) {
            *(float4*)&OL[(size_t)row * HID + tc * 4] =
                make_float4(accL[r][0], accL[r][1], accL[r][2], accL[r][3]);
            *(float4*)&ORp[(size_t)row * HID + tc * 4] =
                make_float4(accR[r][0], accR[r][1], accR[r][2], accR[r][3]);
        }
    }
}

// ---------------- fused GATv2 edge-softmax + aggregation ----------------
// One wave per destination node; lane l owns feature comps 2l,2l+1 (head l>>3).
// Online softmax; self-loop processed first; edge loop unrolled x2.

#define PROC(XLX, XLY)                                                         \
    {                                                                          \
        float t0 = (XLX) + xrv.x; t0 = (t0 > 0.f) ? t0 : NEG_SLOPE * t0;       \
        float t1 = (XLY) + xrv.y; t1 = (t1 > 0.f) ? t1 : NEG_SLOPE * t1;       \
        float p = t0 * attv.x + t1 * attv.y;                                   \
        p += __shfl_xor(p, 1);                                                 \
        p += __shfl_xor(p, 2);                                                 \
        p += __shfl_xor(p, 4);                                                 \
        float mnew = fmaxf(m, p);                                              \
        float scale = __expf(m - mnew);                                        \
        float w = __expf(p - mnew);                                            \
        den = den * scale + w;                                                 \
        acc0 = acc0 * scale + w * (XLX);                                       \
        acc1 = acc1 * scale + w * (XLY);                                       \
        m = mnew;                                                              \
    }

__global__ __launch_bounds__(256) void aggregate_kernel(const float* __restrict__ xl,
                                                        const float* __restrict__ xr,
                                                        const float* __restrict__ att,
                                                        const float* __restrict__ bias,
                                                        const int* __restrict__ off,
                                                        const int* __restrict__ esrc,
                                                        float* __restrict__ out,
                                                        int n, int do_relu) {
    int node = blockIdx.x * (blockDim.x >> 6) + (threadIdx.x >> 6);
    if (node >= n) return;
    const int lane = threadIdx.x & 63;

    const float2 xrv = ((const float2*)(xr + (size_t)node * HID))[lane];
    const float2 attv = ((const float2*)att)[lane];

    float m = -INFINITY, den = 0.f, acc0 = 0.f, acc1 = 0.f;
    const int start = off[node], end = off[node + 1];

    // self-loop (softmax is order-invariant)
    {
        float2 xlv = ((const float2*)(xl + (size_t)node * HID))[lane];
        PROC(xlv.x, xlv.y);
    }
    int j = start;
    for (; j + 1 < end; j += 2) {
        int s0 = esrc[j];
        int s1 = esrc[j + 1];
        float2 a = ((const float2*)(xl + (size_t)s0 * HID))[lane];
        float2 b = ((const float2*)(xl + (size_t)s1 * HID))[lane];
        PROC(a.x, a.y);
        PROC(b.x, b.y);
    }
    if (j < end) {
        int s0 = esrc[j];
        float2 a = ((const float2*)(xl + (size_t)s0 * HID))[lane];
        PROC(a.x, a.y);
    }

    const float2 bv = ((const float2*)bias)[lane];
    float inv = 1.0f / den;
    float o0 = acc0 * inv + bv.x;
    float o1 = acc1 * inv + bv.y;
    if (do_relu) { o0 = fmaxf(o0, 0.f); o1 = fmaxf(o1, 0.f); }
    ((float2*)(out + (size_t)node * HID))[lane] = make_float2(o0, o1);
}

// ---------------- launch ----------------

extern "C" void kernel_launch(void* const* d_in, const int* in_sizes, int n_in,
                              void* d_out, int out_size, void* d_ws, size_t ws_size,
                              hipStream_t stream) {
    const float* x     = (const float*)d_in[0];
    const void*  edges = d_in[1];
    const float* Wl1   = (const float*)d_in[2];
    const float* Wr1   = (const float*)d_in[3];
    const float* att1  = (const float*)d_in[4];
    const float* b1    = (const float*)d_in[5];
    const float* Wl2   = (const float*)d_in[6];
    const float* Wr2   = (const float*)d_in[7];
    const float* att2  = (const float*)d_in[8];
    const float* b2    = (const float*)d_in[9];
    float* out = (float*)d_out;

    const int n = in_sizes[0] / HID;
    const int e = in_sizes[1] / 2;   // element count per the harness contract

    char* ws = (char*)d_ws;
    size_t o = 0;
    auto alloc = [&](size_t bytes) -> void* {
        void* p = ws + o;
        o = (o + bytes + 255) & ~(size_t)255;
        return p;
    };
    int* cnt      = (int*)alloc((size_t)n * 4);
    int* off      = (int*)alloc((size_t)(n + 1) * 4);
    int* cursor   = (int*)alloc((size_t)n * 4);
    int* esrc     = (int*)alloc((size_t)e * 4);
    int* tmp      = (int*)alloc((size_t)n * 4);
    int* partials = (int*)alloc(64 * 4);
    int* is64     = (int*)alloc(256);
    float* A      = (float*)alloc((size_t)n * HID * 4);   // xl
    float* B      = (float*)alloc((size_t)n * HID * 4);   // xr
    float* H      = out;                                   // layer-1 output lives in d_out

    const int nchunks = (n + 1023) / 1024;   // 49 for n=50000 (<=64 required)

    // CSR by destination (shared by both layers)
    detect64_kernel<<<1, 64, 0, stream>>>((const int*)edges, is64, 2LL * e);
    zero_cnt_kernel<<<(n + 255) / 256, 256, 0, stream>>>(cnt, n);
    hist_kernel<<<(e + 255) / 256, 256, 0, stream>>>(edges, is64, cnt, e);
    scan1_kernel<<<nchunks, 256, 0, stream>>>(cnt, tmp, partials, n);
    scan2_kernel<<<1, 64, 0, stream>>>(partials, nchunks, off + n);
    scan3_kernel<<<(n + 255) / 256, 256, 0, stream>>>(tmp, partials, off, cursor, n);
    scatter_kernel<<<(e + 255) / 256, 256, 0, stream>>>(edges, is64, cursor, esrc, e);

    const int gblocks = (n + 63) / 64;

    // layer 1
    gemm_dual_kernel<<<gblocks, 256, 0, stream>>>(x, Wl1, Wr1, A, B, n);
    aggregate_kernel<<<(n + 3) / 4, 256, 0, stream>>>(A, B, att1, b1, off, esrc, H, n, 1);

    // layer 2
    gemm_dual_kernel<<<gblocks, 256, 0, stream>>>(H, Wl2, Wr2, A, B, n);
    aggregate_kernel<<<(n + 3) / 4, 256, 0, stream>>>(A, B, att2, b2, off, esrc, out, n, 0);
}